// Round 3
// baseline (121.442 us; speedup 1.0000x reference)
//
#include <hip/hip_runtime.h>

typedef float f32x4 __attribute__((ext_vector_type(4)));

// Closed-form polar projection of 2x2 W (= U @ Vh from SVD), then compose
// with phase rotation R(phi) = [[c,-s],[s,c]]:  M = R * polar(W).
__device__ __forceinline__ void compute_M(const float4* __restrict__ W,
                                          const float* __restrict__ phase,
                                          int g,
                                          float& m00, float& m01,
                                          float& m10, float& m11) {
    float4 w = W[g];                 // [a b; c d] row-major
    float a = w.x, b = w.y, c = w.z, d = w.w;
    float det = a * d - b * c;
    float q00, q01, q10, q11;
    if (det >= 0.0f) {               // nearest rotation
        float p = a + d, q = b - c;
        float inv = rsqrtf(p * p + q * q);
        q00 = p * inv;  q01 = q * inv;
        q10 = -q * inv; q11 = p * inv;
    } else {                         // nearest reflection
        float p = a - d, q = b + c;
        float inv = rsqrtf(p * p + q * q);
        q00 = p * inv; q01 = q * inv;
        q10 = q * inv; q11 = -p * inv;
    }
    float cs, sn;
    __sincosf(phase[g], &sn, &cs);
    m00 = cs * q00 - sn * q10;
    m01 = cs * q01 - sn * q11;
    m10 = sn * q00 + cs * q10;
    m11 = sn * q01 + cs * q11;
}

// Fused streaming kernel, 4x unrolled grid-stride. Each lane handles one
// float4 (= two channel pairs) per unroll slot; 4 independent nontemporal
// loads are issued back-to-back so each wave keeps 64B in flight, then
// 32 FMAs, then 4 stores. Group index g0 = (2*i) & (G-1) is loop-invariant
// because stride is a multiple of C/4.
__global__ __launch_bounds__(256) void bsu_fused(const f32x4* __restrict__ x,
                                                 const float4* __restrict__ W,
                                                 const float* __restrict__ phase,
                                                 f32x4* __restrict__ y,
                                                 int n4, int gmask) {
    int i0 = blockIdx.x * 256 + threadIdx.x;
    int stride = gridDim.x * 256;
    int g0 = (2 * i0) & gmask;       // even -> g0+1 never wraps

    float a00, a01, a10, a11;        // M[g0]
    float b00, b01, b10, b11;        // M[g0+1]
    compute_M(W, phase, g0,     a00, a01, a10, a11);
    compute_M(W, phase, g0 + 1, b00, b01, b10, b11);

    int i = i0;
    for (; i + 3 * stride < n4; i += 4 * stride) {
        f32x4 v0 = __builtin_nontemporal_load(&x[i]);
        f32x4 v1 = __builtin_nontemporal_load(&x[i + stride]);
        f32x4 v2 = __builtin_nontemporal_load(&x[i + 2 * stride]);
        f32x4 v3 = __builtin_nontemporal_load(&x[i + 3 * stride]);
        f32x4 o0, o1, o2, o3;
        o0.x = a00 * v0.x + a01 * v0.y;  o0.y = a10 * v0.x + a11 * v0.y;
        o0.z = b00 * v0.z + b01 * v0.w;  o0.w = b10 * v0.z + b11 * v0.w;
        o1.x = a00 * v1.x + a01 * v1.y;  o1.y = a10 * v1.x + a11 * v1.y;
        o1.z = b00 * v1.z + b01 * v1.w;  o1.w = b10 * v1.z + b11 * v1.w;
        o2.x = a00 * v2.x + a01 * v2.y;  o2.y = a10 * v2.x + a11 * v2.y;
        o2.z = b00 * v2.z + b01 * v2.w;  o2.w = b10 * v2.z + b11 * v2.w;
        o3.x = a00 * v3.x + a01 * v3.y;  o3.y = a10 * v3.x + a11 * v3.y;
        o3.z = b00 * v3.z + b01 * v3.w;  o3.w = b10 * v3.z + b11 * v3.w;
        __builtin_nontemporal_store(o0, &y[i]);
        __builtin_nontemporal_store(o1, &y[i + stride]);
        __builtin_nontemporal_store(o2, &y[i + 2 * stride]);
        __builtin_nontemporal_store(o3, &y[i + 3 * stride]);
    }
    for (; i < n4; i += stride) {    // defensive tail (empty for 8*4096*2048)
        f32x4 v = __builtin_nontemporal_load(&x[i]);
        f32x4 o;
        o.x = a00 * v.x + a01 * v.y;
        o.y = a10 * v.x + a11 * v.y;
        o.z = b00 * v.z + b01 * v.w;
        o.w = b10 * v.z + b11 * v.w;
        __builtin_nontemporal_store(o, &y[i]);
    }
}

extern "C" void kernel_launch(void* const* d_in, const int* in_sizes, int n_in,
                              void* d_out, int out_size, void* d_ws, size_t ws_size,
                              hipStream_t stream) {
    const float* x     = (const float*)d_in[0];   // [B,T,C] f32
    const float* Wp    = (const float*)d_in[1];   // [G,2,2] f32
    const float* phase = (const float*)d_in[2];   // [G] f32
    float* y = (float*)d_out;

    int G = in_sizes[2];             // 1024
    int n = in_sizes[0];             // B*T*C = 67,108,864
    int n4 = n / 4;                  // 16,777,216 float4s

    // 2048 blocks * 256 threads = 524288 = 1024 * (G/2) -> stride is a
    // multiple of float4s-per-row, keeping g0 loop-invariant per thread.
    int blocks = 2048;
    int row4 = G / 2;                // float4s per C-row
    if ((blocks * 256) % row4 != 0) blocks = (n4 + 255) / 256;

    bsu_fused<<<blocks, 256, 0, stream>>>((const f32x4*)x, (const float4*)Wp,
                                          phase, (f32x4*)y, n4, G - 1);
}

// Round 4
// 97.648 us; speedup vs baseline: 1.2437x; 1.2437x over previous
//
#include <hip/hip_runtime.h>

typedef float f32x4 __attribute__((ext_vector_type(4)));

// Closed-form polar projection of 2x2 W (= U @ Vh from SVD), then compose
// with phase rotation R(phi) = [[c,-s],[s,c]]:  M = R * polar(W).
__device__ __forceinline__ void compute_M(const float4* __restrict__ W,
                                          const float* __restrict__ phase,
                                          int g,
                                          float& m00, float& m01,
                                          float& m10, float& m11) {
    float4 w = W[g];                 // [a b; c d] row-major
    float a = w.x, b = w.y, c = w.z, d = w.w;
    float det = a * d - b * c;
    float q00, q01, q10, q11;
    if (det >= 0.0f) {               // nearest rotation
        float p = a + d, q = b - c;
        float inv = rsqrtf(p * p + q * q);
        q00 = p * inv;  q01 = q * inv;
        q10 = -q * inv; q11 = p * inv;
    } else {                         // nearest reflection
        float p = a - d, q = b + c;
        float inv = rsqrtf(p * p + q * q);
        q00 = p * inv; q01 = q * inv;
        q10 = q * inv; q11 = -p * inv;
    }
    float cs, sn;
    __sincosf(phase[g], &sn, &cs);
    m00 = cs * q00 - sn * q10;
    m01 = cs * q01 - sn * q11;
    m10 = sn * q00 + cs * q10;
    m11 = sn * q01 + cs * q11;
}

#define APPLY(o, m, v)                         \
    o.x = m##00 * v.x + m##01 * v.y;           \
    o.y = m##10 * v.x + m##11 * v.y;           \
    o.z = m##00 * v.z + m##01 * v.w;           \
    o.w = m##10 * v.z + m##11 * v.w;

// Windowed streaming kernel. Each block owns contiguous 1024-float4 (16 KB)
// windows; thread t covers slots t, t+256, t+512, t+768 -> 4 fully-coalesced
// loads only 4 KB apart (one contiguous in-flight region per wave, preserving
// DRAM row locality). A window = 2 C-rows, so slot group indices are
// loop-invariant: even slots use pair g=2t, odd slots pair g=2t+512.
// NOTE: one float4 = 2 channel pairs of the SAME... no: float4 spans pairs
// (2i, 2i+1) -> two adjacent groups. Even slots: groups (2t, 2t+1);
// odd slots: groups (2t+512, 2t+513).
__global__ __launch_bounds__(256) void bsu_win(const f32x4* __restrict__ x,
                                               const float4* __restrict__ W,
                                               const float* __restrict__ phase,
                                               f32x4* __restrict__ y,
                                               int nwin, int gmask) {
    int t = threadIdx.x;
    int gA = (2 * t) & gmask;            // even slots: groups gA, gA+1
    int gB = (2 * (t + 256)) & gmask;    // odd slots:  groups gB, gB+1

    float a00, a01, a10, a11;  // M[gA]
    float c00, c01, c10, c11;  // M[gA+1]
    float e00, e01, e10, e11;  // M[gB]
    float f00, f01, f10, f11;  // M[gB+1]
    compute_M(W, phase, gA,     a00, a01, a10, a11);
    compute_M(W, phase, gA + 1, c00, c01, c10, c11);
    compute_M(W, phase, gB,     e00, e01, e10, e11);
    compute_M(W, phase, gB + 1, f00, f01, f10, f11);

    for (int w = blockIdx.x; w < nwin; w += gridDim.x) {
        int base = w * 1024 + t;
        f32x4 v0 = __builtin_nontemporal_load(&x[base]);
        f32x4 v1 = __builtin_nontemporal_load(&x[base + 256]);
        f32x4 v2 = __builtin_nontemporal_load(&x[base + 512]);
        f32x4 v3 = __builtin_nontemporal_load(&x[base + 768]);
        f32x4 o0, o1, o2, o3;
        // v = (x[2g], x[2g+1], x[2g+2], x[2g+3]) -> first pair uses M[g],
        // second pair uses M[g+1].
        o0.x = a00 * v0.x + a01 * v0.y;  o0.y = a10 * v0.x + a11 * v0.y;
        o0.z = c00 * v0.z + c01 * v0.w;  o0.w = c10 * v0.z + c11 * v0.w;
        o1.x = e00 * v1.x + e01 * v1.y;  o1.y = e10 * v1.x + e11 * v1.y;
        o1.z = f00 * v1.z + f01 * v1.w;  o1.w = f10 * v1.z + f11 * v1.w;
        o2.x = a00 * v2.x + a01 * v2.y;  o2.y = a10 * v2.x + a11 * v2.y;
        o2.z = c00 * v2.z + c01 * v2.w;  o2.w = c10 * v2.z + c11 * v2.w;
        o3.x = e00 * v3.x + e01 * v3.y;  o3.y = e10 * v3.x + e11 * v3.y;
        o3.z = f00 * v3.z + f01 * v3.w;  o3.w = f10 * v3.z + f11 * v3.w;
        __builtin_nontemporal_store(o0, &y[base]);
        __builtin_nontemporal_store(o1, &y[base + 256]);
        __builtin_nontemporal_store(o2, &y[base + 512]);
        __builtin_nontemporal_store(o3, &y[base + 768]);
    }
}

// Fallback (round-2 structure): simple grid-stride, loop-invariant group.
__global__ __launch_bounds__(256) void bsu_fused(const f32x4* __restrict__ x,
                                                 const float4* __restrict__ W,
                                                 const float* __restrict__ phase,
                                                 f32x4* __restrict__ y,
                                                 int n4, int gmask) {
    int i0 = blockIdx.x * 256 + threadIdx.x;
    int stride = gridDim.x * 256;
    int g0 = (2 * i0) & gmask;

    float a00, a01, a10, a11;
    float b00, b01, b10, b11;
    compute_M(W, phase, g0,     a00, a01, a10, a11);
    compute_M(W, phase, g0 + 1, b00, b01, b10, b11);

    for (int i = i0; i < n4; i += stride) {
        f32x4 v = __builtin_nontemporal_load(&x[i]);
        f32x4 o;
        o.x = a00 * v.x + a01 * v.y;
        o.y = a10 * v.x + a11 * v.y;
        o.z = b00 * v.z + b01 * v.w;
        o.w = b10 * v.z + b11 * v.w;
        __builtin_nontemporal_store(o, &y[i]);
    }
}

extern "C" void kernel_launch(void* const* d_in, const int* in_sizes, int n_in,
                              void* d_out, int out_size, void* d_ws, size_t ws_size,
                              hipStream_t stream) {
    const float* x     = (const float*)d_in[0];   // [B,T,C] f32
    const float* Wp    = (const float*)d_in[1];   // [G,2,2] f32
    const float* phase = (const float*)d_in[2];   // [G] f32
    float* y = (float*)d_out;

    int G = in_sizes[2];             // 1024
    int n = in_sizes[0];             // B*T*C = 67,108,864
    int n4 = n / 4;                  // 16,777,216 float4s
    int row4 = G / 2;                // float4s per C-row (512)

    bool pow2G = (G & (G - 1)) == 0;
    // Windowed kernel requires: pow2 G, window (1024 float4s) a multiple of
    // the row width, and n4 a multiple of the window size.
    if (pow2G && row4 > 0 && (1024 % row4) == 0 && (n4 % 1024) == 0) {
        int nwin = n4 / 1024;        // 16384
        bsu_win<<<2048, 256, 0, stream>>>((const f32x4*)x, (const float4*)Wp,
                                          phase, (f32x4*)y, nwin, G - 1);
    } else {
        int blocks = 2048;
        if (!pow2G || (blocks * 256) % row4 != 0) blocks = (n4 + 255) / 256;
        bsu_fused<<<blocks, 256, 0, stream>>>((const f32x4*)x,
                                              (const float4*)Wp, phase,
                                              (f32x4*)y, n4, G - 1);
    }
}